// Round 8
// baseline (87.660 us; speedup 1.0000x reference)
//
#include <hip/hip_runtime.h>
#include <hip/hip_bf16.h>

typedef __bf16 bf16x8 __attribute__((ext_vector_type(8)));
typedef __bf16 bf16x4 __attribute__((ext_vector_type(4)));
typedef float  f32x4  __attribute__((ext_vector_type(4)));

#define LDP 72  // padded LDS row stride in bf16 elems (144B)

// Raw barrier (proj only): drain DS, keep global prefetch loads in flight.
#define BAR() { asm volatile("s_waitcnt lgkmcnt(0)" ::: "memory"); __builtin_amdgcn_s_barrier(); }

// ---------------- Kernel 0a: W -> bf16 pre-conversion ----------------
__global__ __launch_bounds__(256) void wconv_kernel(
    const float* __restrict__ Wk, const float* __restrict__ Wq,
    const float* __restrict__ Wv, __bf16* __restrict__ wbf)
{
    int idx = blockIdx.x * 256 + threadIdx.x;      // 0 .. 49151
    int row = idx >> 8;
    int c4  = idx & 255;
    const float* wp = (row < 64) ? Wk + (size_t)row * 1024
                    : (row < 128) ? Wq + (size_t)(row - 64) * 1024
                                  : Wv + (size_t)(row - 128) * 1024;
    float4 f = *reinterpret_cast<const float4*>(wp + c4 * 4);
    bf16x4 v; v[0] = (__bf16)f.x; v[1] = (__bf16)f.y; v[2] = (__bf16)f.z; v[3] = (__bf16)f.w;
    *reinterpret_cast<bf16x4*>(&wbf[(size_t)row * 1024 + c4 * 4]) = v;
}

// ---------------- Kernel 0b: pack attention_mask into bitwords ----------------
__global__ __launch_bounds__(512) void maskpack_kernel(
    const int* __restrict__ mask, unsigned* __restrict__ maskw)
{
    int wdx = threadIdx.x;   // 0..511 (one block)
    unsigned wv = 0;
    #pragma unroll
    for (int bit = 0; bit < 32; bit++)
        wv |= (mask[wdx * 32 + bit] != 0 ? 1u : 0u) << bit;
    maskw[wdx] = wv;
}

// ---------------- Kernel 1: fused QKV projection GEMM (depth-2 pipeline) ----------------
__global__ __launch_bounds__(1024) void proj_kernel(
    const float* __restrict__ x, const __bf16* __restrict__ wbf,
    __bf16* __restrict__ kbuf, __bf16* __restrict__ qbuf, __bf16* __restrict__ vtbuf)
{
    __shared__ __align__(16) __bf16 Slds[2][256 * LDP];
    __shared__ __align__(16) __bf16 Vtl[64 * LDP];

    const int tid  = threadIdx.x;
    const int lane = tid & 63;
    const int wid  = tid >> 6;     // 0..15
    const int wm   = wid >> 2;     // 0..3 : 16-row group
    const int wn   = wid & 3;      // 0..3 : 48-col group
    const int mbase = blockIdx.x * 64;

    const int cl = lane & 15;
    const int e0 = (lane >> 4) * 8;
    const int r0 = (lane >> 4) * 4;

    const int arow = tid >> 4, acg = tid & 15;
    const float* aptr = x + (size_t)(mbase + arow) * 1024 + acg * 4;

    float4 a0, a1;
    bf16x4 w0[3], w1[3];

#define ISSUE(aset, wset, kb) { \
    aset = *reinterpret_cast<const float4*>(aptr + (kb)); \
    _Pragma("unroll") \
    for (int i_ = 0; i_ < 3; i_++) { \
        int c_ = i_ * 1024 + tid; \
        wset[i_] = *reinterpret_cast<const bf16x4*>(&wbf[(size_t)(c_ >> 4) * 1024 + (kb) + (c_ & 15) * 4]); \
    } }

#define COMMIT(aset, wset, bufi) { \
    bf16x4 av_; \
    av_[0] = (__bf16)aset.x; av_[1] = (__bf16)aset.y; av_[2] = (__bf16)aset.z; av_[3] = (__bf16)aset.w; \
    *reinterpret_cast<bf16x4*>(&Slds[bufi][arow * LDP + acg * 4]) = av_; \
    _Pragma("unroll") \
    for (int i_ = 0; i_ < 3; i_++) { \
        int c_ = i_ * 1024 + tid; \
        *reinterpret_cast<bf16x4*>(&Slds[bufi][(64 + (c_ >> 4)) * LDP + (c_ & 15) * 4]) = wset[i_]; \
    } }

    f32x4 acc[3];
    #pragma unroll
    for (int n = 0; n < 3; n++) acc[n] = (f32x4){0.f, 0.f, 0.f, 0.f};

    ISSUE(a0, w0, 0);
    COMMIT(a0, w0, 0);
    ISSUE(a1, w1, 64);
    BAR();

    #pragma unroll 2
    for (int j = 0; j < 16; j++) {
        if (j < 14) {
            if (j & 1) { ISSUE(a1, w1, (j + 2) * 64); }
            else       { ISSUE(a0, w0, (j + 2) * 64); }
        }
        const __bf16* buf = Slds[j & 1];
        #pragma unroll
        for (int kk = 0; kk < 2; kk++) {
            bf16x8 a = *reinterpret_cast<const bf16x8*>(&buf[(wm * 16 + cl) * LDP + kk * 32 + e0]);
            #pragma unroll
            for (int nf = 0; nf < 3; nf++) {
                bf16x8 b = *reinterpret_cast<const bf16x8*>(&buf[(64 + wn * 48 + nf * 16 + cl) * LDP + kk * 32 + e0]);
                acc[nf] = __builtin_amdgcn_mfma_f32_16x16x32_bf16(a, b, acc[nf], 0, 0, 0);
            }
        }
        if (j < 15) {
            if (j & 1) { COMMIT(a0, w0, 0); }
            else       { COMMIT(a1, w1, 1); }
            BAR();
        }
    }
#undef ISSUE
#undef COMMIT

    #pragma unroll
    for (int nf = 0; nf < 3; nf++) {
        int c = wn * 48 + nf * 16 + cl;
        #pragma unroll
        for (int r = 0; r < 4; r++) {
            int mrel = wm * 16 + r0 + r;
            float v = acc[nf][r];
            if (c < 64)        kbuf[(size_t)(mbase + mrel) * 64 + c]         = (__bf16)v;
            else if (c < 128)  qbuf[(size_t)(mbase + mrel) * 64 + (c - 64)]  = (__bf16)v;
            else               Vtl[(c - 128) * LDP + mrel]                   = (__bf16)v;
        }
    }
    __syncthreads();
    {
        int b   = mbase >> 11;
        int tof = mbase & 2047;
        int h   = tid >> 4;
        int seg = tid & 15;
        bf16x4 v4 = *reinterpret_cast<const bf16x4*>(&Vtl[h * LDP + seg * 4]);
        *reinterpret_cast<bf16x4*>(&vtbuf[(size_t)b * 64 * 2048 + (size_t)h * 2048 + tof + seg * 4]) = v4;
    }
}

// ---------------- Kernel 2: flash attention, barrier-free, direct K/V from L2 ----------------
// K/V = 512KB/batch (L2-resident): no LDS staging, no __syncthreads. MFMA B-operand
// fragments are coalesced 16B global loads; waves fully independent. Only LDS is the
// wave-private P tile (same-wave in-order DS, compiler lgkmcnt). Register prefetch:
// V issued before softmax, K(t+1) before PV (parity-unrolled named sets).
// XCD swizzle: b = wgid&7 -> each XCD's L2 caches ~one batch's KV.
__global__ __launch_bounds__(256) void attn_kernel(
    const __bf16* __restrict__ qbuf, const __bf16* __restrict__ kbuf,
    const __bf16* __restrict__ vtbuf, const unsigned* __restrict__ maskw,
    const int* __restrict__ mask,
    float* __restrict__ out, float* __restrict__ accpart, float* __restrict__ mlpart,
    int nsplit, int tps)
{
    __shared__ __align__(16) __bf16 Plds[4][16 * LDP];

    const int tid  = threadIdx.x;
    const int lane = tid & 63;
    const int w    = tid >> 6;
    const int wg   = blockIdx.x;
    const int b    = wg & 7;            // XCD-local batch
    const int rr_  = wg >> 3;
    const int qt   = rr_ & 31;
    const int sp   = rr_ >> 5;
    const int qbase = qt * 64 + w * 16;

    const int jbeg = sp * tps;
    const int jend = min((sp + 1) * tps, qt + 1);

    if (nsplit > 1 && jbeg >= jend) {
        float* ap = accpart + ((size_t)(b * nsplit + sp) * 2048 + qt * 64) * 64;
        for (int i = tid; i < 64 * 64; i += 256) ap[i] = 0.f;
        float* mp = mlpart + ((size_t)(b * nsplit + sp) * 2048 + qt * 64) * 2;
        for (int i = tid; i < 64; i += 256) { mp[2 * i] = -INFINITY; mp[2 * i + 1] = 0.f; }
        return;
    }

    const int cl = lane & 15;
    const int e0 = (lane >> 4) * 8;
    const int r0 = (lane >> 4) * 4;
    const int qs = qbase + cl;          // q-row this lane owns in S^T layout

    bf16x8 aq[2];
    #pragma unroll
    for (int kk = 0; kk < 2; kk++)
        aq[kk] = *reinterpret_cast<const bf16x8*>(&qbuf[((size_t)b * 2048 + qs) * 64 + kk * 32 + e0]);

    float m = -INFINITY, l = 0.f;
    f32x4 acc[4];
    #pragma unroll
    for (int hf = 0; hf < 4; hf++) acc[hf] = (f32x4){0.f, 0.f, 0.f, 0.f};

    const __bf16* kb = kbuf + (size_t)b * 2048 * 64;
    const __bf16* vtb = vtbuf + (size_t)b * 64 * 2048;

    bf16x8 kfA[8], kfB[8], vf[8];   // [jf*2+kk] / [hf*2+kk]

#define KLOAD(dst, jj) { \
    _Pragma("unroll") \
    for (int f_ = 0; f_ < 8; f_++) { \
        int jf_ = f_ >> 1, kk_ = f_ & 1; \
        dst[f_] = *reinterpret_cast<const bf16x8*>(&kb[(size_t)((jj) * 64 + jf_ * 16 + cl) * 64 + kk_ * 32 + e0]); \
    } }

#define VLOAD(dst, jj) { \
    _Pragma("unroll") \
    for (int f_ = 0; f_ < 8; f_++) { \
        int hf_ = f_ >> 1, kk_ = f_ & 1; \
        dst[f_] = *reinterpret_cast<const bf16x8*>(&vtb[(size_t)(hf_ * 16 + cl) * 2048 + (jj) * 64 + kk_ * 32 + e0]); \
    } }

#define TILE_BODY(KFC, KFN) { \
    /* S^T = K Q^T: s[jf][r] = S[kv = jf*16 + r0 + r][q = qs] */ \
    f32x4 s[4]; \
    _Pragma("unroll") \
    for (int jf = 0; jf < 4; jf++) { \
        f32x4 tacc = (f32x4){0.f, 0.f, 0.f, 0.f}; \
        _Pragma("unroll") \
        for (int kk = 0; kk < 2; kk++) \
            tacc = __builtin_amdgcn_mfma_f32_16x16x32_bf16(KFC[jf * 2 + kk], aq[kk], tacc, 0, 0, 0); \
        s[jf] = tacc; \
    } \
    VLOAD(vf, j);                     /* V in flight during softmax */ \
    const unsigned mw0 = maskw[b * 64 + j * 2]; \
    const unsigned mw1 = maskw[b * 64 + j * 2 + 1]; \
    float tmax = -INFINITY; \
    _Pragma("unroll") \
    for (int jf = 0; jf < 4; jf++) { \
        unsigned mw = (jf < 2) ? mw0 : mw1; \
        _Pragma("unroll") \
        for (int r = 0; r < 4; r++) { \
            int kvl = jf * 16 + r0 + r; \
            bool ok = ((mw >> (kvl & 31)) & 1u) && (j * 64 + kvl <= qs); \
            float sv = s[jf][r] * 0.125f; \
            sv = ok ? sv : -INFINITY; \
            s[jf][r] = sv; \
            tmax = fmaxf(tmax, sv); \
        } \
    } \
    tmax = fmaxf(tmax, __shfl_xor(tmax, 16)); \
    tmax = fmaxf(tmax, __shfl_xor(tmax, 32)); \
    float mn = fmaxf(m, tmax); \
    float alpha = (mn == -INFINITY) ? 1.0f : __expf(m - mn); \
    float rs = 0.f; \
    _Pragma("unroll") \
    for (int jf = 0; jf < 4; jf++) \
        _Pragma("unroll") \
        for (int r = 0; r < 4; r++) { \
            float p = (mn == -INFINITY) ? 0.f : __expf(s[jf][r] - mn); \
            s[jf][r] = p; \
            rs += p; \
        } \
    rs += __shfl_xor(rs, 16); \
    rs += __shfl_xor(rs, 32); \
    l = l * alpha + rs; \
    m = mn; \
    if (t + 1 < nt) KLOAD(KFN, j + 1);   /* next K in flight during PV */ \
    _Pragma("unroll") \
    for (int r = 0; r < 4; r++) { \
        float ar = __shfl(alpha, r0 + r); \
        _Pragma("unroll") \
        for (int hf = 0; hf < 4; hf++) acc[hf][r] *= ar; \
    } \
    _Pragma("unroll") \
    for (int jf = 0; jf < 4; jf++) { \
        bf16x4 p4; \
        _Pragma("unroll") \
        for (int r = 0; r < 4; r++) p4[r] = (__bf16)s[jf][r]; \
        *reinterpret_cast<bf16x4*>(&Plds[w][cl * LDP + jf * 16 + r0]) = p4; \
    } \
    _Pragma("unroll") \
    for (int kk = 0; kk < 2; kk++) { \
        bf16x8 ap = *reinterpret_cast<const bf16x8*>(&Plds[w][cl * LDP + kk * 32 + e0]); \
        _Pragma("unroll") \
        for (int hf = 0; hf < 4; hf++) \
            acc[hf] = __builtin_amdgcn_mfma_f32_16x16x32_bf16(ap, vf[hf * 2 + kk], acc[hf], 0, 0, 0); \
    } }

    const int nt = jend - jbeg;
    KLOAD(kfA, jbeg);
    for (int t = 0; t < nt; t++) {
        const int j = jbeg + t;
        if (t & 1) { TILE_BODY(kfB, kfA); }
        else       { TILE_BODY(kfA, kfB); }
    }
#undef KLOAD
#undef VLOAD
#undef TILE_BODY

    if (nsplit == 1) {
        #pragma unroll
        for (int r = 0; r < 4; r++) {
            int qrow = qbase + r0 + r;
            float lq = __shfl(l, r0 + r);
            int mq = mask[b * 2048 + qrow];
            #pragma unroll
            for (int hf = 0; hf < 4; hf++) {
                float v = (lq > 0.f && mq != 0) ? acc[hf][r] / lq : 0.f;
                out[((size_t)b * 2048 + qrow) * 64 + hf * 16 + cl] = v;
            }
        }
    } else {
        #pragma unroll
        for (int hf = 0; hf < 4; hf++)
            #pragma unroll
            for (int r = 0; r < 4; r++) {
                int qrow = qbase + r0 + r;
                accpart[((size_t)(b * nsplit + sp) * 2048 + qrow) * 64 + hf * 16 + cl] = acc[hf][r];
            }
        if (lane < 16) {
            int qrow = qbase + lane;
            mlpart[((size_t)(b * nsplit + sp) * 2048 + qrow) * 2 + 0] = m;
            mlpart[((size_t)(b * nsplit + sp) * 2048 + qrow) * 2 + 1] = l;
        }
    }
}

// ---------------- Kernel 3: combine split partials ----------------
template<int NS>
__global__ __launch_bounds__(256) void combine_kernel(
    const float* __restrict__ accpart, const float* __restrict__ mlpart,
    const int* __restrict__ mask, float* __restrict__ out)
{
    int idx = blockIdx.x * 256 + threadIdx.x;
    int qglob = idx >> 6;
    int h = idx & 63;
    int b = qglob >> 11;
    int qrow = qglob & 2047;

    if (mask[qglob] == 0) { out[idx] = 0.f; return; }

    float m_s[NS], l_s[NS];
    float M = -INFINITY;
    #pragma unroll
    for (int s = 0; s < NS; s++) {
        size_t mo = ((size_t)(b * NS + s) * 2048 + qrow) * 2;
        m_s[s] = mlpart[mo];
        l_s[s] = mlpart[mo + 1];
        M = fmaxf(M, m_s[s]);
    }
    if (M == -INFINITY) { out[idx] = 0.f; return; }

    float L = 0.f, O = 0.f;
    #pragma unroll
    for (int s = 0; s < NS; s++) {
        float wgt = (m_s[s] == -INFINITY) ? 0.f : __expf(m_s[s] - M);
        L += l_s[s] * wgt;
        O += wgt * accpart[((size_t)(b * NS + s) * 2048 + qrow) * 64 + h];
    }
    out[idx] = (L > 0.f) ? O / L : 0.f;
}

extern "C" void kernel_launch(void* const* d_in, const int* in_sizes, int n_in,
                              void* d_out, int out_size, void* d_ws, size_t ws_size,
                              hipStream_t stream) {
    const float* x  = (const float*)d_in[0];
    const float* Wk = (const float*)d_in[1];
    const float* Wq = (const float*)d_in[2];
    const float* Wv = (const float*)d_in[3];
    const int* mask = (const int*)d_in[4];
    float* out = (float*)d_out;

    const size_t NTOK = 8 * 2048;
    __bf16* kbuf  = (__bf16*)d_ws;                    // [16384][64]
    __bf16* qbuf  = kbuf + NTOK * 64;                 // [16384][64]
    __bf16* vtbuf = qbuf + NTOK * 64;                 // [8][64][2048]
    __bf16* wbf   = vtbuf + (size_t)8 * 64 * 2048;    // [192][1024]
    unsigned* maskw = (unsigned*)(wbf + (size_t)192 * 1024);   // [512]
    const size_t base_bytes = NTOK * 64 * 2 * 2 + (size_t)8 * 64 * 2048 * 2
                            + (size_t)192 * 1024 * 2 + 512 * 4;

    const size_t acc_per_split = NTOK * 64 * 4;
    const size_t ml_per_split  = NTOK * 2 * 4;
    int nsplit = 1;
    if (ws_size >= base_bytes + 4 * (acc_per_split + ml_per_split))      nsplit = 4;
    else if (ws_size >= base_bytes + 2 * (acc_per_split + ml_per_split)) nsplit = 2;

    float* accpart = (float*)((char*)d_ws + base_bytes);
    float* mlpart  = accpart + NTOK * 64 * nsplit;

    wconv_kernel<<<192, 256, 0, stream>>>(Wk, Wq, Wv, wbf);
    maskpack_kernel<<<1, 512, 0, stream>>>(mask, maskw);
    proj_kernel<<<256, 1024, 0, stream>>>(x, wbf, kbuf, qbuf, vtbuf);
    attn_kernel<<<8 * 32 * nsplit, 256, 0, stream>>>(
        qbuf, kbuf, vtbuf, maskw, mask, out, accpart, mlpart, nsplit, 32 / nsplit);
    if (nsplit == 4)
        combine_kernel<4><<<(16384 * 64) / 256, 256, 0, stream>>>(accpart, mlpart, mask, out);
    else if (nsplit == 2)
        combine_kernel<2><<<(16384 * 64) / 256, 256, 0, stream>>>(accpart, mlpart, mask, out);
}

// Round 9
// 64.428 us; speedup vs baseline: 1.3606x; 1.3606x over previous
//
#include <hip/hip_runtime.h>
#include <hip/hip_bf16.h>

typedef __bf16 bf16x8 __attribute__((ext_vector_type(8)));
typedef __bf16 bf16x4 __attribute__((ext_vector_type(4)));
typedef float  f32x4  __attribute__((ext_vector_type(4)));

#define LDP 72   // proj LDS row stride (bf16 elems)
#define KLDP 72  // attn K tile row stride: 64 h + pad (144B, 16B-aligned rows)
#define VLDP 40  // attn V/P row stride: 32 kv + pad (80B, 16B-aligned rows)

// Raw barrier: drain DS only; in-flight global loads survive (no vmcnt drain).
#define BAR() { asm volatile("s_waitcnt lgkmcnt(0)" ::: "memory"); __builtin_amdgcn_s_barrier(); }

// ---------------- Kernel 0a: W -> bf16 pre-conversion ----------------
__global__ __launch_bounds__(256) void wconv_kernel(
    const float* __restrict__ Wk, const float* __restrict__ Wq,
    const float* __restrict__ Wv, __bf16* __restrict__ wbf)
{
    int idx = blockIdx.x * 256 + threadIdx.x;      // 0 .. 49151
    int row = idx >> 8;
    int c4  = idx & 255;
    const float* wp = (row < 64) ? Wk + (size_t)row * 1024
                    : (row < 128) ? Wq + (size_t)(row - 64) * 1024
                                  : Wv + (size_t)(row - 128) * 1024;
    float4 f = *reinterpret_cast<const float4*>(wp + c4 * 4);
    bf16x4 v; v[0] = (__bf16)f.x; v[1] = (__bf16)f.y; v[2] = (__bf16)f.z; v[3] = (__bf16)f.w;
    *reinterpret_cast<bf16x4*>(&wbf[(size_t)row * 1024 + c4 * 4]) = v;
}

// ---------------- Kernel 0b: pack attention_mask into bitwords ----------------
__global__ __launch_bounds__(512) void maskpack_kernel(
    const int* __restrict__ mask, unsigned* __restrict__ maskw)
{
    int wdx = threadIdx.x;   // 0..511 (one block)
    unsigned wv = 0;
    #pragma unroll
    for (int bit = 0; bit < 32; bit++)
        wv |= (mask[wdx * 32 + bit] != 0 ? 1u : 0u) << bit;
    maskw[wdx] = wv;
}

// ---------------- Kernel 1: fused QKV projection GEMM (depth-2 pipeline) ----------------
__global__ __launch_bounds__(1024) void proj_kernel(
    const float* __restrict__ x, const __bf16* __restrict__ wbf,
    __bf16* __restrict__ kbuf, __bf16* __restrict__ qbuf, __bf16* __restrict__ vtbuf)
{
    __shared__ __align__(16) __bf16 Slds[2][256 * LDP];
    __shared__ __align__(16) __bf16 Vtl[64 * LDP];

    const int tid  = threadIdx.x;
    const int lane = tid & 63;
    const int wid  = tid >> 6;     // 0..15
    const int wm   = wid >> 2;     // 0..3 : 16-row group
    const int wn   = wid & 3;      // 0..3 : 48-col group
    const int mbase = blockIdx.x * 64;

    const int cl = lane & 15;
    const int e0 = (lane >> 4) * 8;
    const int r0 = (lane >> 4) * 4;

    const int arow = tid >> 4, acg = tid & 15;
    const float* aptr = x + (size_t)(mbase + arow) * 1024 + acg * 4;

    float4 a0, a1;
    bf16x4 w0[3], w1[3];

#define ISSUE(aset, wset, kb) { \
    aset = *reinterpret_cast<const float4*>(aptr + (kb)); \
    _Pragma("unroll") \
    for (int i_ = 0; i_ < 3; i_++) { \
        int c_ = i_ * 1024 + tid; \
        wset[i_] = *reinterpret_cast<const bf16x4*>(&wbf[(size_t)(c_ >> 4) * 1024 + (kb) + (c_ & 15) * 4]); \
    } }

#define COMMIT(aset, wset, bufi) { \
    bf16x4 av_; \
    av_[0] = (__bf16)aset.x; av_[1] = (__bf16)aset.y; av_[2] = (__bf16)aset.z; av_[3] = (__bf16)aset.w; \
    *reinterpret_cast<bf16x4*>(&Slds[bufi][arow * LDP + acg * 4]) = av_; \
    _Pragma("unroll") \
    for (int i_ = 0; i_ < 3; i_++) { \
        int c_ = i_ * 1024 + tid; \
        *reinterpret_cast<bf16x4*>(&Slds[bufi][(64 + (c_ >> 4)) * LDP + (c_ & 15) * 4]) = wset[i_]; \
    } }

    f32x4 acc[3];
    #pragma unroll
    for (int n = 0; n < 3; n++) acc[n] = (f32x4){0.f, 0.f, 0.f, 0.f};

    ISSUE(a0, w0, 0);
    COMMIT(a0, w0, 0);
    ISSUE(a1, w1, 64);
    BAR();

    #pragma unroll 2
    for (int j = 0; j < 16; j++) {
        if (j < 14) {
            if (j & 1) { ISSUE(a1, w1, (j + 2) * 64); }
            else       { ISSUE(a0, w0, (j + 2) * 64); }
        }
        const __bf16* buf = Slds[j & 1];
        #pragma unroll
        for (int kk = 0; kk < 2; kk++) {
            bf16x8 a = *reinterpret_cast<const bf16x8*>(&buf[(wm * 16 + cl) * LDP + kk * 32 + e0]);
            #pragma unroll
            for (int nf = 0; nf < 3; nf++) {
                bf16x8 b = *reinterpret_cast<const bf16x8*>(&buf[(64 + wn * 48 + nf * 16 + cl) * LDP + kk * 32 + e0]);
                acc[nf] = __builtin_amdgcn_mfma_f32_16x16x32_bf16(a, b, acc[nf], 0, 0, 0);
            }
        }
        if (j < 15) {
            if (j & 1) { COMMIT(a0, w0, 0); }
            else       { COMMIT(a1, w1, 1); }
            BAR();
        }
    }
#undef ISSUE
#undef COMMIT

    #pragma unroll
    for (int nf = 0; nf < 3; nf++) {
        int c = wn * 48 + nf * 16 + cl;
        #pragma unroll
        for (int r = 0; r < 4; r++) {
            int mrel = wm * 16 + r0 + r;
            float v = acc[nf][r];
            if (c < 64)        kbuf[(size_t)(mbase + mrel) * 64 + c]         = (__bf16)v;
            else if (c < 128)  qbuf[(size_t)(mbase + mrel) * 64 + (c - 64)]  = (__bf16)v;
            else               Vtl[(c - 128) * LDP + mrel]                   = (__bf16)v;
        }
    }
    __syncthreads();
    {
        int b   = mbase >> 11;
        int tof = mbase & 2047;
        int h   = tid >> 4;
        int seg = tid & 15;
        bf16x4 v4 = *reinterpret_cast<const bf16x4*>(&Vtl[h * LDP + seg * 4]);
        *reinterpret_cast<bf16x4*>(&vtbuf[(size_t)b * 64 * 2048 + (size_t)h * 2048 + tof + seg * 4]) = v4;
    }
}

// ---------------- Kernel 2: flash attention, dbuf KVBLK=32, one barrier/tile ----------------
// grid (8*32*nsplit), 256 threads = 4 waves; wave w owns 16 q rows. Swapped QK
// (S^T: lane holds one q-row) AND swapped PV (O^T: q stays lane-local -> zero
// broadcast shuffles). K/V staged in double-buffered LDS shared by all 4 waves
// (L2-resident data, staged once per block); commit targets the idle buffer so
// ONE lgkm-only barrier per tile; staging loads covered by a full tile of compute.
__global__ __launch_bounds__(256) void attn_kernel(
    const __bf16* __restrict__ qbuf, const __bf16* __restrict__ kbuf,
    const __bf16* __restrict__ vtbuf, const unsigned* __restrict__ maskw,
    const int* __restrict__ mask,
    float* __restrict__ out, float* __restrict__ accpart, float* __restrict__ mlpart,
    int nsplit, int tps)
{
    __shared__ __align__(16) __bf16 Klds[2][32 * KLDP];   // [kv row][h]
    __shared__ __align__(16) __bf16 Vlds[2][64 * VLDP];   // [h row][kv]
    __shared__ __align__(16) __bf16 Plds[4][16 * VLDP];   // per-wave [q row][kv]

    const int tid  = threadIdx.x;
    const int lane = tid & 63;
    const int w    = tid >> 6;
    const int wg   = blockIdx.x;
    const int b    = wg & 7;            // XCD-local batch
    const int rr_  = wg >> 3;
    const int qt   = rr_ & 31;
    const int sp   = rr_ >> 5;
    const int qbase = qt * 64 + w * 16;

    const int jbeg = sp * tps;
    const int jend = min((sp + 1) * tps, 2 * qt + 2);   // kv tiles are 32 wide

    if (nsplit > 1 && jbeg >= jend) {
        float* ap = accpart + ((size_t)(b * nsplit + sp) * 2048 + qt * 64) * 64;
        for (int i = tid; i < 64 * 64; i += 256) ap[i] = 0.f;
        float* mp = mlpart + ((size_t)(b * nsplit + sp) * 2048 + qt * 64) * 2;
        for (int i = tid; i < 64; i += 256) { mp[2 * i] = -INFINITY; mp[2 * i + 1] = 0.f; }
        return;
    }

    const int cl = lane & 15;
    const int e0 = (lane >> 4) * 8;
    const int r0 = (lane >> 4) * 4;
    const int qs = qbase + cl;          // q-row this lane owns (S^T and O^T layouts)

    bf16x8 aq[2];
    #pragma unroll
    for (int kk = 0; kk < 2; kk++)
        aq[kk] = *reinterpret_cast<const bf16x8*>(&qbuf[((size_t)b * 2048 + qs) * 64 + kk * 32 + e0]);

    float m = -INFINITY, l = 0.f;       // softmax state for q = qs
    f32x4 acc[4];                       // acc[hf][r] = O^T[h = hf*16 + r0 + r][q = qs]
    #pragma unroll
    for (int hf = 0; hf < 4; hf++) acc[hf] = (f32x4){0.f, 0.f, 0.f, 0.f};

    const __bf16* kb  = kbuf  + (size_t)b * 2048 * 64;
    const __bf16* vtb = vtbuf + (size_t)b * 64 * 2048;

    // staging: K tile 32x64 (thread -> row tid>>3, 8-elem chunk tid&7);
    //          V tile 64 h-rows x 32 kv (thread -> row tid>>2, chunk tid&3)
    const int krow = tid >> 3, kcg = tid & 7;
    const int vrow = tid >> 2, vcg = tid & 3;
    bf16x8 st_k, st_v;

#define KV_ISSUE(jj) { \
    st_k = *reinterpret_cast<const bf16x8*>(&kb[(size_t)((jj) * 32 + krow) * 64 + kcg * 8]); \
    st_v = *reinterpret_cast<const bf16x8*>(&vtb[(size_t)vrow * 2048 + (jj) * 32 + vcg * 8]); }

#define KV_COMMIT(bi) { \
    *reinterpret_cast<bf16x8*>(&Klds[bi][krow * KLDP + kcg * 8]) = st_k; \
    *reinterpret_cast<bf16x8*>(&Vlds[bi][vrow * VLDP + vcg * 8]) = st_v; }

    const int nt = jend - jbeg;
    KV_ISSUE(jbeg);
    KV_COMMIT(0);
    if (nt > 1) KV_ISSUE(jbeg + 1);
    BAR();

    for (int t = 0; t < nt; t++) {
        const int j = jbeg + t;
        const int cur = t & 1;

        // commit tile t+1 into the idle buffer (its loads issued a full tile ago)
        if (t + 1 < nt) KV_COMMIT(cur ^ 1);
        // issue tile t+2 (in flight across this tile's compute + barrier)
        if (t + 2 < nt) KV_ISSUE(j + 2);

        // S^T = K Q^T: s[jf][r] = S[kv = jf*16 + r0 + r][q = qs]
        f32x4 s[2];
        #pragma unroll
        for (int jf = 0; jf < 2; jf++) {
            f32x4 tacc = (f32x4){0.f, 0.f, 0.f, 0.f};
            #pragma unroll
            for (int kk = 0; kk < 2; kk++) {
                bf16x8 bk = *reinterpret_cast<const bf16x8*>(&Klds[cur][(jf * 16 + cl) * KLDP + kk * 32 + e0]);
                tacc = __builtin_amdgcn_mfma_f32_16x16x32_bf16(bk, aq[kk], tacc, 0, 0, 0);
            }
            s[jf] = tacc;
        }

        // scale + causal & column mask (one bitword per 32-kv tile)
        const unsigned mw = maskw[b * 64 + j];
        float tmax = -INFINITY;
        #pragma unroll
        for (int jf = 0; jf < 2; jf++)
            #pragma unroll
            for (int r = 0; r < 4; r++) {
                int kvl = jf * 16 + r0 + r;              // 0..31
                bool ok = ((mw >> kvl) & 1u) && (j * 32 + kvl <= qs);
                float sv = s[jf][r] * 0.125f;
                sv = ok ? sv : -INFINITY;
                s[jf][r] = sv;
                tmax = fmaxf(tmax, sv);
            }
        tmax = fmaxf(tmax, __shfl_xor(tmax, 16));
        tmax = fmaxf(tmax, __shfl_xor(tmax, 32));

        float mn = fmaxf(m, tmax);
        float alpha = (mn == -INFINITY) ? 1.0f : __expf(m - mn);
        float rs = 0.f;
        #pragma unroll
        for (int jf = 0; jf < 2; jf++)
            #pragma unroll
            for (int r = 0; r < 4; r++) {
                float p = (mn == -INFINITY) ? 0.f : __expf(s[jf][r] - mn);
                s[jf][r] = p;
                rs += p;
            }
        rs += __shfl_xor(rs, 16);
        rs += __shfl_xor(rs, 32);
        l = l * alpha + rs;
        m = mn;

        // O^T rescale: q is lane-local -> no broadcast shuffles
        #pragma unroll
        for (int hf = 0; hf < 4; hf++)
            #pragma unroll
            for (int r = 0; r < 4; r++) acc[hf][r] *= alpha;

        // P -> wave-private LDS as [q][kv] (write column q = cl)
        #pragma unroll
        for (int jf = 0; jf < 2; jf++) {
            bf16x4 p4;
            #pragma unroll
            for (int r = 0; r < 4; r++) p4[r] = (__bf16)s[jf][r];
            *reinterpret_cast<bf16x4*>(&Plds[w][cl * VLDP + jf * 16 + r0]) = p4;
        }
        // O^T += V^T P^T: mfma(A = Vt rows h, B = P rows q), k-dim = 32 (one mfma/hf)
        {
            bf16x8 pb = *reinterpret_cast<const bf16x8*>(&Plds[w][cl * VLDP + e0]);
            #pragma unroll
            for (int hf = 0; hf < 4; hf++) {
                bf16x8 av = *reinterpret_cast<const bf16x8*>(&Vlds[cur][(hf * 16 + cl) * VLDP + e0]);
                acc[hf] = __builtin_amdgcn_mfma_f32_16x16x32_bf16(av, pb, acc[hf], 0, 0, 0);
            }
        }

        if (t + 1 < nt) BAR();   // commits visible; next tile's buffer ready
    }
#undef KV_ISSUE
#undef KV_COMMIT

    if (nsplit == 1) {
        int mq = mask[b * 2048 + qs];
        #pragma unroll
        for (int hf = 0; hf < 4; hf++)
            #pragma unroll
            for (int r = 0; r < 4; r++) {
                float v = (l > 0.f && mq != 0) ? acc[hf][r] / l : 0.f;
                out[((size_t)b * 2048 + qs) * 64 + hf * 16 + r0 + r] = v;
            }
    } else {
        #pragma unroll
        for (int hf = 0; hf < 4; hf++)
            #pragma unroll
            for (int r = 0; r < 4; r++)
                accpart[((size_t)(b * nsplit + sp) * 2048 + qs) * 64 + hf * 16 + r0 + r] = acc[hf][r];
        if (lane < 16) {                 // lanes 0..15 hold (m,l) for q = qbase+lane
            int qrow = qbase + lane;
            mlpart[((size_t)(b * nsplit + sp) * 2048 + qrow) * 2 + 0] = m;
            mlpart[((size_t)(b * nsplit + sp) * 2048 + qrow) * 2 + 1] = l;
        }
    }
}

// ---------------- Kernel 3: combine split partials ----------------
template<int NS>
__global__ __launch_bounds__(256) void combine_kernel(
    const float* __restrict__ accpart, const float* __restrict__ mlpart,
    const int* __restrict__ mask, float* __restrict__ out)
{
    int idx = blockIdx.x * 256 + threadIdx.x;
    int qglob = idx >> 6;
    int h = idx & 63;
    int b = qglob >> 11;
    int qrow = qglob & 2047;

    if (mask[qglob] == 0) { out[idx] = 0.f; return; }

    float m_s[NS], l_s[NS];
    float M = -INFINITY;
    #pragma unroll
    for (int s = 0; s < NS; s++) {
        size_t mo = ((size_t)(b * NS + s) * 2048 + qrow) * 2;
        m_s[s] = mlpart[mo];
        l_s[s] = mlpart[mo + 1];
        M = fmaxf(M, m_s[s]);
    }
    if (M == -INFINITY) { out[idx] = 0.f; return; }

    float L = 0.f, O = 0.f;
    #pragma unroll
    for (int s = 0; s < NS; s++) {
        float wgt = (m_s[s] == -INFINITY) ? 0.f : __expf(m_s[s] - M);
        L += l_s[s] * wgt;
        O += wgt * accpart[((size_t)(b * NS + s) * 2048 + qrow) * 64 + h];
    }
    out[idx] = (L > 0.f) ? O / L : 0.f;
}

extern "C" void kernel_launch(void* const* d_in, const int* in_sizes, int n_in,
                              void* d_out, int out_size, void* d_ws, size_t ws_size,
                              hipStream_t stream) {
    const float* x  = (const float*)d_in[0];
    const float* Wk = (const float*)d_in[1];
    const float* Wq = (const float*)d_in[2];
    const float* Wv = (const float*)d_in[3];
    const int* mask = (const int*)d_in[4];
    float* out = (float*)d_out;

    const size_t NTOK = 8 * 2048;
    __bf16* kbuf  = (__bf16*)d_ws;                    // [16384][64]
    __bf16* qbuf  = kbuf + NTOK * 64;                 // [16384][64]
    __bf16* vtbuf = qbuf + NTOK * 64;                 // [8][64][2048]
    __bf16* wbf   = vtbuf + (size_t)8 * 64 * 2048;    // [192][1024]
    unsigned* maskw = (unsigned*)(wbf + (size_t)192 * 1024);   // [512]
    const size_t base_bytes = NTOK * 64 * 2 * 2 + (size_t)8 * 64 * 2048 * 2
                            + (size_t)192 * 1024 * 2 + 512 * 4;

    const size_t acc_per_split = NTOK * 64 * 4;
    const size_t ml_per_split  = NTOK * 2 * 4;
    int nsplit = 1;
    if (ws_size >= base_bytes + 4 * (acc_per_split + ml_per_split))      nsplit = 4;
    else if (ws_size >= base_bytes + 2 * (acc_per_split + ml_per_split)) nsplit = 2;

    float* accpart = (float*)((char*)d_ws + base_bytes);
    float* mlpart  = accpart + NTOK * 64 * nsplit;

    wconv_kernel<<<192, 256, 0, stream>>>(Wk, Wq, Wv, wbf);
    maskpack_kernel<<<1, 512, 0, stream>>>(mask, maskw);
    proj_kernel<<<256, 1024, 0, stream>>>(x, wbf, kbuf, qbuf, vtbuf);
    attn_kernel<<<8 * 32 * nsplit, 256, 0, stream>>>(
        qbuf, kbuf, vtbuf, maskw, mask, out, accpart, mlpart, nsplit, 64 / nsplit);
    if (nsplit == 4)
        combine_kernel<4><<<(16384 * 64) / 256, 256, 0, stream>>>(accpart, mlpart, mask, out);
    else if (nsplit == 2)
        combine_kernel<2><<<(16384 * 64) / 256, 256, 0, stream>>>(accpart, mlpart, mask, out);
}

// Round 10
// 58.205 us; speedup vs baseline: 1.5060x; 1.1069x over previous
//
#include <hip/hip_runtime.h>
#include <hip/hip_bf16.h>

typedef __bf16 bf16x8 __attribute__((ext_vector_type(8)));
typedef __bf16 bf16x4 __attribute__((ext_vector_type(4)));
typedef float  f32x4  __attribute__((ext_vector_type(4)));

#define LDP  72  // proj LDS row stride
#define KLDP 72  // attn K row stride (64 h + pad)
#define VLDP 72  // attn V row stride (64 kv + pad)
#define PLDP 72  // attn P row stride (64 kv + pad)

// Raw barrier: drain DS only; in-flight global loads survive (no vmcnt drain).
#define BAR() { asm volatile("s_waitcnt lgkmcnt(0)" ::: "memory"); __builtin_amdgcn_s_barrier(); }

// ---------------- Kernel 0: W -> bf16 + maskpack (fused) ----------------
// blocks 0..191: convert W rows; block 192: pack attention_mask into bitwords.
__global__ __launch_bounds__(256) void wconv_kernel(
    const float* __restrict__ Wk, const float* __restrict__ Wq,
    const float* __restrict__ Wv, const int* __restrict__ mask,
    __bf16* __restrict__ wbf, unsigned* __restrict__ maskw)
{
    if (blockIdx.x == 192) {
        for (int wdx = threadIdx.x; wdx < 512; wdx += 256) {
            unsigned wv = 0;
            #pragma unroll
            for (int bit = 0; bit < 32; bit++)
                wv |= (mask[wdx * 32 + bit] != 0 ? 1u : 0u) << bit;
            maskw[wdx] = wv;
        }
        return;
    }
    int idx = blockIdx.x * 256 + threadIdx.x;      // 0 .. 49151
    int row = idx >> 8;
    int c4  = idx & 255;
    const float* wp = (row < 64) ? Wk + (size_t)row * 1024
                    : (row < 128) ? Wq + (size_t)(row - 64) * 1024
                                  : Wv + (size_t)(row - 128) * 1024;
    float4 f = *reinterpret_cast<const float4*>(wp + c4 * 4);
    bf16x4 v; v[0] = (__bf16)f.x; v[1] = (__bf16)f.y; v[2] = (__bf16)f.z; v[3] = (__bf16)f.w;
    *reinterpret_cast<bf16x4*>(&wbf[(size_t)row * 1024 + c4 * 4]) = v;
}

// ---------------- Kernel 1: fused QKV projection GEMM (depth-2 pipeline) ----------------
__global__ __launch_bounds__(1024) void proj_kernel(
    const float* __restrict__ x, const __bf16* __restrict__ wbf,
    __bf16* __restrict__ kbuf, __bf16* __restrict__ qbuf, __bf16* __restrict__ vtbuf)
{
    __shared__ __align__(16) __bf16 Slds[2][256 * LDP];
    __shared__ __align__(16) __bf16 Vtl[64 * LDP];

    const int tid  = threadIdx.x;
    const int lane = tid & 63;
    const int wid  = tid >> 6;     // 0..15
    const int wm   = wid >> 2;     // 0..3
    const int wn   = wid & 3;      // 0..3
    const int mbase = blockIdx.x * 64;

    const int cl = lane & 15;
    const int e0 = (lane >> 4) * 8;
    const int r0 = (lane >> 4) * 4;

    const int arow = tid >> 4, acg = tid & 15;
    const float* aptr = x + (size_t)(mbase + arow) * 1024 + acg * 4;

    float4 a0, a1;
    bf16x4 w0[3], w1[3];

#define ISSUE(aset, wset, kb) { \
    aset = *reinterpret_cast<const float4*>(aptr + (kb)); \
    _Pragma("unroll") \
    for (int i_ = 0; i_ < 3; i_++) { \
        int c_ = i_ * 1024 + tid; \
        wset[i_] = *reinterpret_cast<const bf16x4*>(&wbf[(size_t)(c_ >> 4) * 1024 + (kb) + (c_ & 15) * 4]); \
    } }

#define COMMIT(aset, wset, bufi) { \
    bf16x4 av_; \
    av_[0] = (__bf16)aset.x; av_[1] = (__bf16)aset.y; av_[2] = (__bf16)aset.z; av_[3] = (__bf16)aset.w; \
    *reinterpret_cast<bf16x4*>(&Slds[bufi][arow * LDP + acg * 4]) = av_; \
    _Pragma("unroll") \
    for (int i_ = 0; i_ < 3; i_++) { \
        int c_ = i_ * 1024 + tid; \
        *reinterpret_cast<bf16x4*>(&Slds[bufi][(64 + (c_ >> 4)) * LDP + (c_ & 15) * 4]) = wset[i_]; \
    } }

    f32x4 acc[3];
    #pragma unroll
    for (int n = 0; n < 3; n++) acc[n] = (f32x4){0.f, 0.f, 0.f, 0.f};

    ISSUE(a0, w0, 0);
    COMMIT(a0, w0, 0);
    ISSUE(a1, w1, 64);
    BAR();

    #pragma unroll 2
    for (int j = 0; j < 16; j++) {
        if (j < 14) {
            if (j & 1) { ISSUE(a1, w1, (j + 2) * 64); }
            else       { ISSUE(a0, w0, (j + 2) * 64); }
        }
        const __bf16* buf = Slds[j & 1];
        #pragma unroll
        for (int kk = 0; kk < 2; kk++) {
            bf16x8 a = *reinterpret_cast<const bf16x8*>(&buf[(wm * 16 + cl) * LDP + kk * 32 + e0]);
            #pragma unroll
            for (int nf = 0; nf < 3; nf++) {
                bf16x8 b = *reinterpret_cast<const bf16x8*>(&buf[(64 + wn * 48 + nf * 16 + cl) * LDP + kk * 32 + e0]);
                acc[nf] = __builtin_amdgcn_mfma_f32_16x16x32_bf16(a, b, acc[nf], 0, 0, 0);
            }
        }
        if (j < 15) {
            if (j & 1) { COMMIT(a0, w0, 0); }
            else       { COMMIT(a1, w1, 1); }
            BAR();
        }
    }
#undef ISSUE
#undef COMMIT

    #pragma unroll
    for (int nf = 0; nf < 3; nf++) {
        int c = wn * 48 + nf * 16 + cl;
        #pragma unroll
        for (int r = 0; r < 4; r++) {
            int mrel = wm * 16 + r0 + r;
            float v = acc[nf][r];
            if (c < 64)        kbuf[(size_t)(mbase + mrel) * 64 + c]         = (__bf16)v;
            else if (c < 128)  qbuf[(size_t)(mbase + mrel) * 64 + (c - 64)]  = (__bf16)v;
            else               Vtl[(c - 128) * LDP + mrel]                   = (__bf16)v;
        }
    }
    __syncthreads();
    {
        int b   = mbase >> 11;
        int tof = mbase & 2047;
        int h   = tid >> 4;
        int seg = tid & 15;
        bf16x4 v4 = *reinterpret_cast<const bf16x4*>(&Vtl[h * LDP + seg * 4]);
        *reinterpret_cast<bf16x4*>(&vtbuf[(size_t)b * 64 * 2048 + (size_t)h * 2048 + tof + seg * 4]) = v4;
    }
}

// ---------------- Kernel 2: flash attention, 2 waves x 2 q-subtiles (ILP) ----------------
// grid (8*32*nsplit) blocks of 128 threads = 2 waves; block owns 64 q rows.
// Wave w owns subtiles at rows {w*16, 32+w*16}: the two softmax chains are
// independent (ILP) and SHARE the K/V fragment reads, mask words, barriers and
// staging -> per-q-row orchestration halves vs 1-subtile waves. Swapped QK and
// swapped PV keep q lane-local (no broadcast shuffles). KVBLK=64, single LDS
// buffer, register prefetch 1 tile ahead, 2 lgkm-only barriers per tile.
__global__ __launch_bounds__(128) void attn_kernel(
    const __bf16* __restrict__ qbuf, const __bf16* __restrict__ kbuf,
    const __bf16* __restrict__ vtbuf, const unsigned* __restrict__ maskw,
    float* __restrict__ out, float* __restrict__ accpart, float* __restrict__ mlpart,
    int nsplit, int tps)
{
    __shared__ __align__(16) __bf16 Klds[64 * KLDP];        // [kv][h]
    __shared__ __align__(16) __bf16 Vlds[64 * VLDP];        // [h][kv]
    __shared__ __align__(16) __bf16 Plds[2][2][16 * PLDP];  // [wave][sub][q][kv]

    const int tid  = threadIdx.x;
    const int lane = tid & 63;
    const int w    = tid >> 6;          // 0..1
    const int wg   = blockIdx.x;
    const int b    = wg & 7;            // XCD-local batch
    const int rr_  = wg >> 3;
    const int qt   = rr_ & 31;
    const int sp   = rr_ >> 5;

    const int jbeg = sp * tps;
    const int jend = min((sp + 1) * tps, qt + 1);   // 64-wide kv tiles

    if (nsplit > 1 && jbeg >= jend) {
        // empty split: ml only; accpart left unwritten (combine weight = 0)
        for (int i = tid; i < 64; i += 128) {
            size_t mo = ((size_t)(b * nsplit + sp) * 2048 + qt * 64 + i) * 2;
            mlpart[mo] = -INFINITY; mlpart[mo + 1] = 0.f;
        }
        return;
    }

    const int cl = lane & 15;
    const int e0 = (lane >> 4) * 8;
    const int r0 = (lane >> 4) * 4;
    const int qs0 = qt * 64 + w * 16 + cl;   // subtile 0 q-row (lane-local)
    const int qs1 = qs0 + 32;                // subtile 1 q-row

    bf16x8 aq0[2], aq1[2];
    #pragma unroll
    for (int kk = 0; kk < 2; kk++) {
        aq0[kk] = *reinterpret_cast<const bf16x8*>(&qbuf[((size_t)b * 2048 + qs0) * 64 + kk * 32 + e0]);
        aq1[kk] = *reinterpret_cast<const bf16x8*>(&qbuf[((size_t)b * 2048 + qs1) * 64 + kk * 32 + e0]);
    }

    float m0 = -INFINITY, l0 = 0.f, m1 = -INFINITY, l1 = 0.f;
    f32x4 acc0[4], acc1[4];
    #pragma unroll
    for (int hf = 0; hf < 4; hf++) { acc0[hf] = (f32x4){0.f,0.f,0.f,0.f}; acc1[hf] = (f32x4){0.f,0.f,0.f,0.f}; }

    const __bf16* kb  = kbuf  + (size_t)b * 2048 * 64;
    const __bf16* vtb = vtbuf + (size_t)b * 64 * 2048;

    // staging: 128 threads, thread -> row tid>>1 (0..63), 32-elem half (tid&1)
    const int srow = tid >> 1;
    const int sc   = (tid & 1) * 32;
    bf16x8 stk[4], stv[4];

#define KV_ISSUE(jj) { _Pragma("unroll") for (int i_ = 0; i_ < 4; i_++) { \
    stk[i_] = *reinterpret_cast<const bf16x8*>(&kb[(size_t)((jj) * 64 + srow) * 64 + sc + i_ * 8]); \
    stv[i_] = *reinterpret_cast<const bf16x8*>(&vtb[(size_t)srow * 2048 + (jj) * 64 + sc + i_ * 8]); } }

#define KV_COMMIT() { _Pragma("unroll") for (int i_ = 0; i_ < 4; i_++) { \
    *reinterpret_cast<bf16x8*>(&Klds[srow * KLDP + sc + i_ * 8]) = stk[i_]; \
    *reinterpret_cast<bf16x8*>(&Vlds[srow * VLDP + sc + i_ * 8]) = stv[i_]; } }

// softmax + P-write for one subtile (independent chain; su is a literal)
#define SOFTMAX(S, mS, lS, accS, qsS, su) { \
    float tmax = -INFINITY; \
    _Pragma("unroll") for (int jf = 0; jf < 4; jf++) { \
        unsigned mw = (jf < 2) ? mw0 : mw1; \
        _Pragma("unroll") for (int r = 0; r < 4; r++) { \
            int kvl = jf * 16 + r0 + r; \
            bool ok = ((mw >> (kvl & 31)) & 1u) && (j * 64 + kvl <= qsS); \
            float sv = S[jf][r] * 0.125f; \
            sv = ok ? sv : -INFINITY; \
            S[jf][r] = sv; tmax = fmaxf(tmax, sv); } } \
    tmax = fmaxf(tmax, __shfl_xor(tmax, 16)); \
    tmax = fmaxf(tmax, __shfl_xor(tmax, 32)); \
    float mn = fmaxf(mS, tmax); \
    float alpha = (mn == -INFINITY) ? 1.0f : __expf(mS - mn); \
    float rs = 0.f; \
    _Pragma("unroll") for (int jf = 0; jf < 4; jf++) \
        _Pragma("unroll") for (int r = 0; r < 4; r++) { \
            float p = (mn == -INFINITY) ? 0.f : __expf(S[jf][r] - mn); \
            S[jf][r] = p; rs += p; } \
    rs += __shfl_xor(rs, 16); \
    rs += __shfl_xor(rs, 32); \
    lS = lS * alpha + rs; mS = mn; \
    _Pragma("unroll") for (int hf = 0; hf < 4; hf++) \
        _Pragma("unroll") for (int r = 0; r < 4; r++) accS[hf][r] *= alpha; \
    _Pragma("unroll") for (int jf = 0; jf < 4; jf++) { \
        bf16x4 p4; \
        _Pragma("unroll") for (int r = 0; r < 4; r++) p4[r] = (__bf16)S[jf][r]; \
        *reinterpret_cast<bf16x4*>(&Plds[w][su][cl * PLDP + jf * 16 + r0]) = p4; } }

    const int nt = jend - jbeg;
    KV_ISSUE(jbeg);
    KV_COMMIT();
    if (nt > 1) KV_ISSUE(jbeg + 1);
    BAR();

    for (int t = 0; t < nt; t++) {
        const int j = jbeg + t;

        // S^T = K Q^T for both subtiles, sharing K fragments
        f32x4 s0[4], s1[4];
        #pragma unroll
        for (int jf = 0; jf < 4; jf++) {
            f32x4 t0 = (f32x4){0.f,0.f,0.f,0.f}, t1 = (f32x4){0.f,0.f,0.f,0.f};
            #pragma unroll
            for (int kk = 0; kk < 2; kk++) {
                bf16x8 bk = *reinterpret_cast<const bf16x8*>(&Klds[(jf * 16 + cl) * KLDP + kk * 32 + e0]);
                t0 = __builtin_amdgcn_mfma_f32_16x16x32_bf16(bk, aq0[kk], t0, 0, 0, 0);
                t1 = __builtin_amdgcn_mfma_f32_16x16x32_bf16(bk, aq1[kk], t1, 0, 0, 0);
            }
            s0[jf] = t0; s1[jf] = t1;
        }

        const unsigned mw0 = maskw[b * 64 + j * 2];
        const unsigned mw1 = maskw[b * 64 + j * 2 + 1];
        SOFTMAX(s0, m0, l0, acc0, qs0, 0);
        SOFTMAX(s1, m1, l1, acc1, qs1, 1);

        // O^T += V^T P^T for both subtiles, sharing V fragments (same-wave P lgkm dep)
        #pragma unroll
        for (int kk = 0; kk < 2; kk++) {
            bf16x8 p0 = *reinterpret_cast<const bf16x8*>(&Plds[w][0][cl * PLDP + kk * 32 + e0]);
            bf16x8 p1 = *reinterpret_cast<const bf16x8*>(&Plds[w][1][cl * PLDP + kk * 32 + e0]);
            #pragma unroll
            for (int hf = 0; hf < 4; hf++) {
                bf16x8 av = *reinterpret_cast<const bf16x8*>(&Vlds[(hf * 16 + cl) * VLDP + kk * 32 + e0]);
                acc0[hf] = __builtin_amdgcn_mfma_f32_16x16x32_bf16(av, p0, acc0[hf], 0, 0, 0);
                acc1[hf] = __builtin_amdgcn_mfma_f32_16x16x32_bf16(av, p1, acc1[hf], 0, 0, 0);
            }
        }

        BAR();                       // all waves done reading K/V
        if (t + 1 < nt) {
            KV_COMMIT();             // overwrite with tile t+1 (loads landed: counted vmcnt)
            if (t + 2 < nt) KV_ISSUE(j + 2);
            BAR();                   // writes visible before next compute
        }
    }
#undef KV_ISSUE
#undef KV_COMMIT
#undef SOFTMAX

    const bool mq0 = (maskw[b * 64 + (qs0 >> 5)] >> (qs0 & 31)) & 1u;
    const bool mq1 = (maskw[b * 64 + (qs1 >> 5)] >> (qs1 & 31)) & 1u;
    if (nsplit == 1) {
        #pragma unroll
        for (int hf = 0; hf < 4; hf++)
            #pragma unroll
            for (int r = 0; r < 4; r++) {
                float v0 = (l0 > 0.f && mq0) ? acc0[hf][r] / l0 : 0.f;
                float v1 = (l1 > 0.f && mq1) ? acc1[hf][r] / l1 : 0.f;
                out[((size_t)b * 2048 + qs0) * 64 + hf * 16 + r0 + r] = v0;
                out[((size_t)b * 2048 + qs1) * 64 + hf * 16 + r0 + r] = v1;
            }
    } else {
        #pragma unroll
        for (int hf = 0; hf < 4; hf++)
            #pragma unroll
            for (int r = 0; r < 4; r++) {
                accpart[((size_t)(b * nsplit + sp) * 2048 + qs0) * 64 + hf * 16 + r0 + r] = acc0[hf][r];
                accpart[((size_t)(b * nsplit + sp) * 2048 + qs1) * 64 + hf * 16 + r0 + r] = acc1[hf][r];
            }
        if (lane < 16) {
            size_t mo0 = ((size_t)(b * nsplit + sp) * 2048 + qs0) * 2;
            size_t mo1 = ((size_t)(b * nsplit + sp) * 2048 + qs1) * 2;
            mlpart[mo0] = m0; mlpart[mo0 + 1] = l0;
            mlpart[mo1] = m1; mlpart[mo1 + 1] = l1;
        }
    }
}

// ---------------- Kernel 3: combine split partials ----------------
template<int NS>
__global__ __launch_bounds__(256) void combine_kernel(
    const float* __restrict__ accpart, const float* __restrict__ mlpart,
    const unsigned* __restrict__ maskw, float* __restrict__ out)
{
    int idx = blockIdx.x * 256 + threadIdx.x;
    int qglob = idx >> 6;                        // b*2048 + qrow
    int h = idx & 63;
    int b = qglob >> 11;
    int qrow = qglob & 2047;

    if (!((maskw[b * 64 + (qrow >> 5)] >> (qrow & 31)) & 1u)) { out[idx] = 0.f; return; }

    float m_s[NS], l_s[NS];
    float M = -INFINITY;
    #pragma unroll
    for (int s = 0; s < NS; s++) {
        size_t mo = ((size_t)(b * NS + s) * 2048 + qrow) * 2;
        m_s[s] = mlpart[mo];
        l_s[s] = mlpart[mo + 1];
        M = fmaxf(M, m_s[s]);
    }
    if (M == -INFINITY) { out[idx] = 0.f; return; }

    float L = 0.f, O = 0.f;
    #pragma unroll
    for (int s = 0; s < NS; s++) {
        float wgt = (m_s[s] == -INFINITY) ? 0.f : __expf(m_s[s] - M);
        L += l_s[s] * wgt;
        O += wgt * accpart[((size_t)(b * NS + s) * 2048 + qrow) * 64 + h];
    }
    out[idx] = (L > 0.f) ? O / L : 0.f;
}

extern "C" void kernel_launch(void* const* d_in, const int* in_sizes, int n_in,
                              void* d_out, int out_size, void* d_ws, size_t ws_size,
                              hipStream_t stream) {
    const float* x  = (const float*)d_in[0];
    const float* Wk = (const float*)d_in[1];
    const float* Wq = (const float*)d_in[2];
    const float* Wv = (const float*)d_in[3];
    const int* mask = (const int*)d_in[4];
    float* out = (float*)d_out;

    const size_t NTOK = 8 * 2048;
    __bf16* kbuf  = (__bf16*)d_ws;                    // [16384][64]
    __bf16* qbuf  = kbuf + NTOK * 64;                 // [16384][64]
    __bf16* vtbuf = qbuf + NTOK * 64;                 // [8][64][2048]
    __bf16* wbf   = vtbuf + (size_t)8 * 64 * 2048;    // [192][1024]
    unsigned* maskw = (unsigned*)(wbf + (size_t)192 * 1024);   // [512]
    const size_t base_bytes = NTOK * 64 * 2 * 2 + (size_t)8 * 64 * 2048 * 2
                            + (size_t)192 * 1024 * 2 + 512 * 4;

    const size_t acc_per_split = NTOK * 64 * 4;
    const size_t ml_per_split  = NTOK * 2 * 4;
    int nsplit = 1;
    if (ws_size >= base_bytes + 4 * (acc_per_split + ml_per_split))      nsplit = 4;
    else if (ws_size >= base_bytes + 2 * (acc_per_split + ml_per_split)) nsplit = 2;

    float* accpart = (float*)((char*)d_ws + base_bytes);
    float* mlpart  = accpart + NTOK * 64 * nsplit;

    wconv_kernel<<<193, 256, 0, stream>>>(Wk, Wq, Wv, mask, wbf, maskw);
    proj_kernel<<<256, 1024, 0, stream>>>(x, wbf, kbuf, qbuf, vtbuf);
    attn_kernel<<<8 * 32 * nsplit, 128, 0, stream>>>(
        qbuf, kbuf, vtbuf, maskw, out, accpart, mlpart, nsplit, 32 / nsplit);
    if (nsplit == 4)
        combine_kernel<4><<<(16384 * 64) / 256, 256, 0, stream>>>(accpart, mlpart, maskw, out);
    else if (nsplit == 2)
        combine_kernel<2><<<(16384 * 64) / 256, 256, 0, stream>>>(accpart, mlpart, maskw, out);
}